// Round 3
// baseline (100.260 us; speedup 1.0000x reference)
//
#include <hip/hip_runtime.h>
#include <stdint.h>

// Problem constants
#define NROWS 16384    // B*X*Y*Z
#define K_    8192

// GEMM tiling: 256-row m-blocks x 8-way k-split, 128-entry codebook chunks
#define MT      256
#define KC      128
#define KSPLIT  8
#define KSEC    (K_ / KSPLIT)      // 1024
#define NCHUNK  (KSEC / KC)        // 8

typedef __attribute__((ext_vector_type(8))) short short8;
typedef __attribute__((ext_vector_type(4))) float f32x4;

__device__ __forceinline__ unsigned f2bf(float f) {
  union { float f; unsigned u; } v; v.f = f;
  unsigned r = v.u + 0x7FFFu + ((v.u >> 16) & 1u);  // RNE
  return r >> 16;
}

// async global->LDS, 16B per lane: lds wave-uniform base, lane i lands at base+16i.
__device__ __forceinline__ void async_ld16(void* lds, const void* g) {
  __builtin_amdgcn_global_load_lds(
      (const __attribute__((address_space(1))) unsigned int*)g,
      (__attribute__((address_space(3))) unsigned int*)lds, 16, 0, 0);
}

// ---------------------------------------------------------------------------
// Kernel 1 (512 blocks x 256):
//   blocks 0..255  : latents [4,64,4096] f32 -> latT bf16 [16384 rows][64],
//                    XOR-swizzled 16B atoms (atom j -> j ^ (row&7)) so gemm can
//                    stage rows with global_load_lds AND read frags conflict-free.
//   blocks 256..511: codebook -> bf16 swizzled atoms + norms + run[]=~0.
// ---------------------------------------------------------------------------
__global__ __launch_bounds__(256) void vq_prep(
    const float* __restrict__ lat,
    const float* __restrict__ cb,
    uint4* __restrict__ cbb16,      // [K_*8] swizzled atoms
    uint4* __restrict__ latT16,     // [NROWS*8] swizzled atoms
    float* __restrict__ norm2,      // [K_] = 0.75 + 32*||e||^2
    unsigned* __restrict__ run)     // [NROWS]
{
  const int t = threadIdx.x, blk = blockIdx.x;
  if (blk < 256) {
    const int b = blk >> 6, xyz0 = (blk & 63) * 64;
    const float* base = lat + ((size_t)b * 64) * 4096 + xyz0;
#pragma unroll
    for (int i = 0; i < 2; ++i) {
      int p = i * 256 + t;
      int j = p >> 6, r = p & 63;          // j = d-atom, r = row-in-block
      float v0 = base[(j * 8 + 0) * 4096 + r];
      float v1 = base[(j * 8 + 1) * 4096 + r];
      float v2 = base[(j * 8 + 2) * 4096 + r];
      float v3 = base[(j * 8 + 3) * 4096 + r];
      float v4 = base[(j * 8 + 4) * 4096 + r];
      float v5 = base[(j * 8 + 5) * 4096 + r];
      float v6 = base[(j * 8 + 6) * 4096 + r];
      float v7 = base[(j * 8 + 7) * 4096 + r];
      uint4 o;
      o.x = f2bf(v0) | (f2bf(v1) << 16);
      o.y = f2bf(v2) | (f2bf(v3) << 16);
      o.z = f2bf(v4) | (f2bf(v5) << 16);
      o.w = f2bf(v6) | (f2bf(v7) << 16);
      int row = b * 4096 + xyz0 + r;
      latT16[row * 8 + (j ^ (row & 7))] = o;
    }
  } else {
    const int bb = blk - 256;
    const int row = bb * 32 + (t >> 3);
    const int j = t & 7;
    const float4* src = (const float4*)(cb + row * 64 + j * 8);
    float4 v0 = src[0], v1 = src[1];
    float ss = v0.x * v0.x + v0.y * v0.y + v0.z * v0.z + v0.w * v0.w
             + v1.x * v1.x + v1.y * v1.y + v1.z * v1.z + v1.w * v1.w;
    uint4 o;
    o.x = f2bf(v0.x) | (f2bf(v0.y) << 16);
    o.y = f2bf(v0.z) | (f2bf(v0.w) << 16);
    o.z = f2bf(v1.x) | (f2bf(v1.y) << 16);
    o.w = f2bf(v1.z) | (f2bf(v1.w) << 16);
    ss += __shfl_xor(ss, 1);
    ss += __shfl_xor(ss, 2);
    ss += __shfl_xor(ss, 4);
    cbb16[row * 8 + (j ^ (row & 7))] = o;
    if (j == 0) norm2[row] = 0.75f + 32.f * ss;
    if (t < 64) run[bb * 64 + t] = 0xFFFFFFFFu;
  }
}

// ---------------------------------------------------------------------------
// Kernel 2: MFMA GEMM + fused packed-argmin. Grid = 64 m-blocks x KSPLIT = 512
// blocks (2/CU), 256 threads (4 waves x 64 m-rows as 4 m-tiles of 16).
// Both A (once) and B (per chunk) staged via global_load_lds(16B), swizzled.
// ---------------------------------------------------------------------------
__global__ __launch_bounds__(256, 2) void vq_gemm(
    const uint4* __restrict__ latT16,
    const uint4* __restrict__ cbb16,
    const float* __restrict__ norm2,
    unsigned* __restrict__ run)
{
  __shared__ __align__(16) char lA[MT * 128];   // 32768 B
  __shared__ __align__(16) char lB[KC * 128];   // 16384 B
  __shared__ __align__(16) float lN[256];       // 1024 B (128 used + async slop)

  const int t = threadIdx.x;
  const int bm = blockIdx.x & 63;
  const int ks = blockIdx.x >> 6;
  const int row0 = bm * MT;
  const int lane = t & 63, wid = t >> 6;
  const int l15 = lane & 15, q = lane >> 4;

  // Stage A tile: 256 rows x 128 B = 2048 atoms, 8 segs/wave.
#pragma unroll
  for (int i = 0; i < 8; ++i) {
    int seg = i * 4 + wid;
    async_ld16(lA + seg * 1024, latT16 + row0 * 8 + seg * 64 + lane);
  }
  __syncthreads();

  // A fragments: 4 m-tiles x 2 k-steps, held for the whole kernel.
  short8 afr[4][2];
#pragma unroll
  for (int mt = 0; mt < 4; ++mt) {
    int lr = wid * 64 + mt * 16 + l15;
#pragma unroll
    for (int kk = 0; kk < 2; ++kk)
      afr[mt][kk] = *(const short8*)(lA + lr * 128 + (((q + 4 * kk) ^ (l15 & 7)) * 16));
  }

  const f32x4 z4 = {0.f, 0.f, 0.f, 0.f};   // loop-invariant acc init (no per-nt movs)
  unsigned rmin[4][4];
#pragma unroll
  for (int mt = 0; mt < 4; ++mt)
#pragma unroll
    for (int r = 0; r < 4; ++r) rmin[mt][r] = 0xFFFFFFFFu;

  for (int c = 0; c < NCHUNK; ++c) {
    const int kbase = ks * KSEC + c * KC;
    __syncthreads();
    // stage B chunk: 128 rows x 128 B = 1024 atoms, 4 segs/wave + norms
#pragma unroll
    for (int i = 0; i < 4; ++i) {
      int seg = i * 4 + wid;
      async_ld16(lB + seg * 1024, cbb16 + kbase * 8 + seg * 64 + lane);
    }
    if (wid == 0) async_ld16(lN, norm2 + kbase);  // 1024B (128 floats used)
    __syncthreads();

#pragma unroll
    for (int nt = 0; nt < 8; ++nt) {
      int rb = nt * 16 + l15;
      const char* rowp = lB + rb * 128;
      short8 b0 = *(const short8*)(rowp + ((q ^ (rb & 7)) * 16));
      short8 b1 = *(const short8*)(rowp + (((q + 4) ^ (rb & 7)) * 16));
      float n2 = lN[rb];
      unsigned kv = (unsigned)(kbase + rb);
#pragma unroll
      for (int mt = 0; mt < 4; ++mt) {
        f32x4 acc = __builtin_amdgcn_mfma_f32_16x16x32_bf16(afr[mt][0], b0, z4, 0, 0, 0);
        acc = __builtin_amdgcn_mfma_f32_16x16x32_bf16(afr[mt][1], b1, acc, 0, 0, 0);
#pragma unroll
        for (int r = 0; r < 4; ++r) {
          // score = (0.75+32||e||^2) - 64*dot  in (0.5,1): bits monotone
          float s = fmaf(acc[r], -64.f, n2);
          unsigned p = (__float_as_uint(s) & 0xFFFFE000u) | kv;
          rmin[mt][r] = p < rmin[mt][r] ? p : rmin[mt][r];
        }
      }
    }
  }

  // min across the 16 lanes (l15) sharing each C-row
#pragma unroll
  for (int mt = 0; mt < 4; ++mt)
#pragma unroll
    for (int r = 0; r < 4; ++r) {
      unsigned v = rmin[mt][r];
      unsigned o;
      o = (unsigned)__shfl_xor((int)v, 1); v = o < v ? o : v;
      o = (unsigned)__shfl_xor((int)v, 2); v = o < v ? o : v;
      o = (unsigned)__shfl_xor((int)v, 4); v = o < v ? o : v;
      o = (unsigned)__shfl_xor((int)v, 8); v = o < v ? o : v;
      rmin[mt][r] = v;
    }
  if (l15 == 0) {
#pragma unroll
    for (int mt = 0; mt < 4; ++mt)
#pragma unroll
      for (int r = 0; r < 4; ++r)
        atomicMin(&run[row0 + wid * 64 + mt * 16 + q * 4 + r], rmin[mt][r]);
  }
}

// ---------------------------------------------------------------------------
// Kernel 3: gather codebook rows into output layout + per-block loss partial.
// ---------------------------------------------------------------------------
__global__ __launch_bounds__(256) void vq_gather_loss(
    const float* __restrict__ lat,
    const float* __restrict__ cb,
    const unsigned* __restrict__ run,
    float* __restrict__ out,
    float* __restrict__ partials)   // [1024]
{
  const int t = threadIdx.x;
  const int gid = blockIdx.x * 256 + t;
  const int E0 = gid * 4;
  const int xyz = E0 & 4095;
  const int d = (E0 >> 12) & 63;
  const int b = E0 >> 18;
  const int n0 = b * 4096 + xyz;

  float4 l4 = *(const float4*)(lat + E0);
  uint4 i4 = *(const uint4*)(run + n0);
  float q0 = cb[(i4.x & 8191u) * 64 + d];
  float q1 = cb[(i4.y & 8191u) * 64 + d];
  float q2 = cb[(i4.z & 8191u) * 64 + d];
  float q3 = cb[(i4.w & 8191u) * 64 + d];
  *(float4*)(out + E0) = make_float4(q0, q1, q2, q3);

  float d0 = q0 - l4.x, d1 = q1 - l4.y, d2 = q2 - l4.z, d3 = q3 - l4.w;
  float dsum = d0 * d0 + d1 * d1 + d2 * d2 + d3 * d3;
#pragma unroll
  for (int m = 1; m < 64; m <<= 1) dsum += __shfl_xor(dsum, m);

  __shared__ float wsum[4];
  if ((t & 63) == 0) wsum[t >> 6] = dsum;
  __syncthreads();
  if (t == 0) partials[blockIdx.x] = wsum[0] + wsum[1] + wsum[2] + wsum[3];
}

// ---------------------------------------------------------------------------
// Kernel 4: final loss reduction (single block, no atomics).
// ---------------------------------------------------------------------------
__global__ __launch_bounds__(256) void vq_final(
    const float* __restrict__ partials,
    const float* __restrict__ vqw,
    float* __restrict__ out)
{
  const int t = threadIdx.x;
  float4 v = ((const float4*)partials)[t];
  float s = v.x + v.y + v.z + v.w;
#pragma unroll
  for (int m = 1; m < 64; m <<= 1) s += __shfl_xor(s, m);
  __shared__ float wsum[4];
  if ((t & 63) == 0) wsum[t >> 6] = s;
  __syncthreads();
  if (t == 0) {
    float total = wsum[0] + wsum[1] + wsum[2] + wsum[3];
    out[NROWS * 64] = total * (1.f + vqw[0]) / (float)(NROWS * 64);
  }
}

// ---------------------------------------------------------------------------
extern "C" void kernel_launch(void* const* d_in, const int* in_sizes, int n_in,
                              void* d_out, int out_size, void* d_ws, size_t ws_size,
                              hipStream_t stream) {
  const float* lat = (const float*)d_in[0];
  const float* vqw = (const float*)d_in[1];
  const float* cb  = (const float*)d_in[2];
  float* out = (float*)d_out;

  unsigned* ws     = (unsigned*)d_ws;
  uint4*    cbb16  = (uint4*)ws;                    // 65536 uint4  (1 MB)
  uint4*    latT16 = (uint4*)(ws + 262144);         // 131072 uint4 (2 MB)
  float*    norm2  = (float*)(ws + 786432);         // 8192 floats
  unsigned* run    = ws + 786432 + 8192;            // 16384 uints
  float*    partials = (float*)(ws + 786432 + 8192 + 16384); // 1024 floats

  vq_prep<<<512, 256, 0, stream>>>(lat, cb, cbb16, latT16, norm2, run);
  vq_gemm<<<64 * KSPLIT, 256, 0, stream>>>(latT16, cbb16, norm2, run);
  vq_gather_loss<<<1024, 256, 0, stream>>>(lat, cb, run, out, partials);
  vq_final<<<1, 256, 0, stream>>>(partials, vqw, out);
}

// Round 4
// 92.435 us; speedup vs baseline: 1.0847x; 1.0847x over previous
//
#include <hip/hip_runtime.h>
#include <stdint.h>

// Problem constants
#define NROWS 16384    // B*X*Y*Z
#define K_    8192

// GEMM tiling: 256-row m-blocks x 8-way k-split, 128-entry codebook chunks
#define MT      256
#define KC      128
#define KSPLIT  8
#define KSEC    (K_ / KSPLIT)      // 1024
#define NCHUNK  (KSEC / KC)        // 8

typedef __attribute__((ext_vector_type(8))) short short8;
typedef __attribute__((ext_vector_type(4))) float f32x4;

__device__ __forceinline__ unsigned f2bf(float f) {
  union { float f; unsigned u; } v; v.f = f;
  unsigned r = v.u + 0x7FFFu + ((v.u >> 16) & 1u);  // RNE
  return r >> 16;
}

// async global->LDS, 16B per lane: lds wave-uniform base, lane i lands at base+16i.
__device__ __forceinline__ void async_ld16(void* lds, const void* g) {
  __builtin_amdgcn_global_load_lds(
      (const __attribute__((address_space(1))) unsigned int*)g,
      (__attribute__((address_space(3))) unsigned int*)lds, 16, 0, 0);
}

// ---------------------------------------------------------------------------
// Kernel 1 (512 blocks x 256):
//   blocks 0..255  : latents f32 -> latT16 = bf16(-64*x), XOR-swizzled atoms
//                    (atom j -> j ^ (row&7)); ALSO per-block partial of
//                    sum(x^2) (unscaled, fp32) -> xnormp[blk].
//   blocks 256..511: codebook -> bf16 swizzled atoms + norm2 + run[]=~0.
// Pre-scaling A by -64 lets gemm preload C with n2 so the MFMA result IS the
// packed-score float directly (epilogue 3 -> 2 VALU per score).
// ---------------------------------------------------------------------------
__global__ __launch_bounds__(256) void vq_prep(
    const float* __restrict__ lat,
    const float* __restrict__ cb,
    uint4* __restrict__ cbb16,      // [K_*8] swizzled atoms
    uint4* __restrict__ latT16,     // [NROWS*8] swizzled atoms, -64*x
    float* __restrict__ norm2,      // [K_] = 0.75 + 32*||e||^2
    unsigned* __restrict__ run,     // [NROWS]
    float* __restrict__ xnormp)     // [256] partials of sum(x^2)
{
  const int t = threadIdx.x, blk = blockIdx.x;
  if (blk < 256) {
    const int b = blk >> 6, xyz0 = (blk & 63) * 64;
    const float* base = lat + ((size_t)b * 64) * 4096 + xyz0;
    float ss = 0.f;
#pragma unroll
    for (int i = 0; i < 2; ++i) {
      int p = i * 256 + t;
      int j = p >> 6, r = p & 63;          // j = d-atom, r = row-in-block
      float v0 = base[(j * 8 + 0) * 4096 + r];
      float v1 = base[(j * 8 + 1) * 4096 + r];
      float v2 = base[(j * 8 + 2) * 4096 + r];
      float v3 = base[(j * 8 + 3) * 4096 + r];
      float v4 = base[(j * 8 + 4) * 4096 + r];
      float v5 = base[(j * 8 + 5) * 4096 + r];
      float v6 = base[(j * 8 + 6) * 4096 + r];
      float v7 = base[(j * 8 + 7) * 4096 + r];
      ss += v0 * v0 + v1 * v1 + v2 * v2 + v3 * v3
          + v4 * v4 + v5 * v5 + v6 * v6 + v7 * v7;
      uint4 o;
      o.x = f2bf(-64.f * v0) | (f2bf(-64.f * v1) << 16);
      o.y = f2bf(-64.f * v2) | (f2bf(-64.f * v3) << 16);
      o.z = f2bf(-64.f * v4) | (f2bf(-64.f * v5) << 16);
      o.w = f2bf(-64.f * v6) | (f2bf(-64.f * v7) << 16);
      int row = b * 4096 + xyz0 + r;
      latT16[row * 8 + (j ^ (row & 7))] = o;
    }
    // block partial of sum(x^2)
#pragma unroll
    for (int m = 1; m < 64; m <<= 1) ss += __shfl_xor(ss, m);
    __shared__ float wsum[4];
    if ((t & 63) == 0) wsum[t >> 6] = ss;
    __syncthreads();
    if (t == 0) xnormp[blk] = wsum[0] + wsum[1] + wsum[2] + wsum[3];
  } else {
    const int bb = blk - 256;
    const int row = bb * 32 + (t >> 3);
    const int j = t & 7;
    const float4* src = (const float4*)(cb + row * 64 + j * 8);
    float4 v0 = src[0], v1 = src[1];
    float ss = v0.x * v0.x + v0.y * v0.y + v0.z * v0.z + v0.w * v0.w
             + v1.x * v1.x + v1.y * v1.y + v1.z * v1.z + v1.w * v1.w;
    uint4 o;
    o.x = f2bf(v0.x) | (f2bf(v0.y) << 16);
    o.y = f2bf(v0.z) | (f2bf(v0.w) << 16);
    o.z = f2bf(v1.x) | (f2bf(v1.y) << 16);
    o.w = f2bf(v1.z) | (f2bf(v1.w) << 16);
    ss += __shfl_xor(ss, 1);
    ss += __shfl_xor(ss, 2);
    ss += __shfl_xor(ss, 4);
    cbb16[row * 8 + (j ^ (row & 7))] = o;
    if (j == 0) norm2[row] = 0.75f + 32.f * ss;
    if (t < 64) run[bb * 64 + t] = 0xFFFFFFFFu;
  }
}

// ---------------------------------------------------------------------------
// Kernel 2: MFMA GEMM + fused packed-argmin. Grid = 64 m-blocks x KSPLIT = 512
// blocks, 256 threads (4 waves x 64 m-rows as 4 m-tiles of 16).
// A holds -64*x, C preloaded with n2 => MFMA output = packed-score float s
// = 0.75 + 32||e||^2 - 64 x.e directly (s>0 always, bits monotone).
// ---------------------------------------------------------------------------
__global__ __launch_bounds__(256, 2) void vq_gemm(
    const uint4* __restrict__ latT16,
    const uint4* __restrict__ cbb16,
    const float* __restrict__ norm2,
    unsigned* __restrict__ run)
{
  __shared__ __align__(16) char lA[MT * 128];   // 32768 B
  __shared__ __align__(16) char lB[KC * 128];   // 16384 B
  __shared__ __align__(16) float lN[256];       // 1024 B (128 used + async slop)

  const int t = threadIdx.x;
  const int bm = blockIdx.x & 63;
  const int ks = blockIdx.x >> 6;
  const int row0 = bm * MT;
  const int lane = t & 63, wid = t >> 6;
  const int l15 = lane & 15, q = lane >> 4;

  // Stage A tile: 256 rows x 128 B = 2048 atoms, 8 segs/wave.
#pragma unroll
  for (int i = 0; i < 8; ++i) {
    int seg = i * 4 + wid;
    async_ld16(lA + seg * 1024, latT16 + row0 * 8 + seg * 64 + lane);
  }
  __syncthreads();

  // A fragments: 4 m-tiles x 2 k-steps, held for the whole kernel.
  short8 afr[4][2];
#pragma unroll
  for (int mt = 0; mt < 4; ++mt) {
    int lr = wid * 64 + mt * 16 + l15;
#pragma unroll
    for (int kk = 0; kk < 2; ++kk)
      afr[mt][kk] = *(const short8*)(lA + lr * 128 + (((q + 4 * kk) ^ (l15 & 7)) * 16));
  }

  unsigned rmin[4][4];
#pragma unroll
  for (int mt = 0; mt < 4; ++mt)
#pragma unroll
    for (int r = 0; r < 4; ++r) rmin[mt][r] = 0xFFFFFFFFu;

  for (int c = 0; c < NCHUNK; ++c) {
    const int kbase = ks * KSEC + c * KC;
    __syncthreads();
    // stage B chunk: 128 rows x 128 B = 1024 atoms, 4 segs/wave + norms
#pragma unroll
    for (int i = 0; i < 4; ++i) {
      int seg = i * 4 + wid;
      async_ld16(lB + seg * 1024, cbb16 + kbase * 8 + seg * 64 + lane);
    }
    if (wid == 0) async_ld16(lN, norm2 + kbase);
    __syncthreads();

#pragma unroll
    for (int nt = 0; nt < 8; ++nt) {
      int rb = nt * 16 + l15;
      const char* rowp = lB + rb * 128;
      short8 b0 = *(const short8*)(rowp + ((q ^ (rb & 7)) * 16));
      short8 b1 = *(const short8*)(rowp + (((q + 4) ^ (rb & 7)) * 16));
      float n2 = lN[rb];
      f32x4 n2v = {n2, n2, n2, n2};         // C preload (same for all mt)
      unsigned kv = (unsigned)(kbase + rb);
#pragma unroll
      for (int mt = 0; mt < 4; ++mt) {
        f32x4 acc = __builtin_amdgcn_mfma_f32_16x16x32_bf16(afr[mt][0], b0, n2v, 0, 0, 0);
        acc = __builtin_amdgcn_mfma_f32_16x16x32_bf16(afr[mt][1], b1, acc, 0, 0, 0);
#pragma unroll
        for (int r = 0; r < 4; ++r) {
          unsigned p = (__float_as_uint(acc[r]) & 0xFFFFE000u) | kv;
          rmin[mt][r] = p < rmin[mt][r] ? p : rmin[mt][r];
        }
      }
    }
  }

  // min across the 16 lanes (l15) sharing each C-row
#pragma unroll
  for (int mt = 0; mt < 4; ++mt)
#pragma unroll
    for (int r = 0; r < 4; ++r) {
      unsigned v = rmin[mt][r];
      unsigned o;
      o = (unsigned)__shfl_xor((int)v, 1); v = o < v ? o : v;
      o = (unsigned)__shfl_xor((int)v, 2); v = o < v ? o : v;
      o = (unsigned)__shfl_xor((int)v, 4); v = o < v ? o : v;
      o = (unsigned)__shfl_xor((int)v, 8); v = o < v ? o : v;
      rmin[mt][r] = v;
    }
  if (l15 == 0) {
#pragma unroll
    for (int mt = 0; mt < 4; ++mt)
#pragma unroll
      for (int r = 0; r < 4; ++r)
        atomicMin(&run[row0 + wid * 64 + mt * 16 + q * 4 + r], rmin[mt][r]);
  }
}

// ---------------------------------------------------------------------------
// Kernel 3: gather codebook rows into output layout. Block 0 additionally
// computes the loss from the packed argmin words: dist_n = ||x_n||^2 +
// (s_n - 0.75)/32, so NO re-read of the 16 MB latents is needed.
// ---------------------------------------------------------------------------
__global__ __launch_bounds__(256) void vq_gather(
    const float* __restrict__ cb,
    const unsigned* __restrict__ run,
    const float* __restrict__ xnormp,
    const float* __restrict__ vqw,
    float* __restrict__ out)
{
  const int t = threadIdx.x;
  const int gid = blockIdx.x * 256 + t;
  const int E0 = gid * 4;
  const int xyz = E0 & 4095;
  const int d = (E0 >> 12) & 63;
  const int b = E0 >> 18;
  const int n0 = b * 4096 + xyz;

  uint4 i4 = *(const uint4*)(run + n0);
  float q0 = cb[(i4.x & 8191u) * 64 + d];
  float q1 = cb[(i4.y & 8191u) * 64 + d];
  float q2 = cb[(i4.z & 8191u) * 64 + d];
  float q3 = cb[(i4.w & 8191u) * 64 + d];
  *(float4*)(out + E0) = make_float4(q0, q1, q2, q3);

  if (blockIdx.x == 0) {
    // s-sum over all 16384 packed words + xnorm partials
    float ssum = 0.f;
    const uint4* r4 = (const uint4*)run;
#pragma unroll
    for (int i = 0; i < 16; ++i) {
      uint4 u = r4[i * 256 + t];
      ssum += (__uint_as_float(u.x & 0xFFFFE000u) - 0.75f)
            + (__uint_as_float(u.y & 0xFFFFE000u) - 0.75f)
            + (__uint_as_float(u.z & 0xFFFFE000u) - 0.75f)
            + (__uint_as_float(u.w & 0xFFFFE000u) - 0.75f);
    }
    float xs = xnormp[t];
#pragma unroll
    for (int m = 1; m < 64; m <<= 1) {
      ssum += __shfl_xor(ssum, m);
      xs   += __shfl_xor(xs, m);
    }
    __shared__ float wss[4], wxs[4];
    if ((t & 63) == 0) { wss[t >> 6] = ssum; wxs[t >> 6] = xs; }
    __syncthreads();
    if (t == 0) {
      float S = wss[0] + wss[1] + wss[2] + wss[3];
      float X = wxs[0] + wxs[1] + wxs[2] + wxs[3];
      float total = X + S * (1.f / 32.f);
      out[NROWS * 64] = total * (1.f + vqw[0]) / (float)(NROWS * 64);
    }
  }
}

// ---------------------------------------------------------------------------
extern "C" void kernel_launch(void* const* d_in, const int* in_sizes, int n_in,
                              void* d_out, int out_size, void* d_ws, size_t ws_size,
                              hipStream_t stream) {
  const float* lat = (const float*)d_in[0];
  const float* vqw = (const float*)d_in[1];
  const float* cb  = (const float*)d_in[2];
  float* out = (float*)d_out;

  unsigned* ws     = (unsigned*)d_ws;
  uint4*    cbb16  = (uint4*)ws;                    // 65536 uint4  (1 MB)
  uint4*    latT16 = (uint4*)(ws + 262144);         // 131072 uint4 (2 MB)
  float*    norm2  = (float*)(ws + 786432);         // 8192 floats
  unsigned* run    = ws + 786432 + 8192;            // 16384 uints (also async slop for lN)
  float*    xnormp = (float*)(ws + 786432 + 8192 + 16384); // 256 floats

  vq_prep<<<512, 256, 0, stream>>>(lat, cb, cbb16, latT16, norm2, run, xnormp);
  vq_gemm<<<64 * KSPLIT, 256, 0, stream>>>(latT16, cbb16, norm2, run);
  vq_gather<<<1024, 256, 0, stream>>>(cb, run, xnormp, vqw, out);
}